// Round 23
// baseline (435.865 us; speedup 1.0000x reference)
//
#include <hip/hip_runtime.h>
#include <stdint.h>

#define M_DIM 4096
#define K_DIM 4096
#define N_DIM 11008
#define KP    512              // 16B slots (8 fp16) per K row
#define NT    64               // K tiles of 64
#define NTILES 688             // 16 x 43 output tiles of 256x256
#define NWORK  512             // persistent blocks

// ---- FULL path ws layout: Wf fp16 [N][K] + xw fp16 [M][K] ----
#define XW2_OFFSET  92274688u
#define FULL_NEEDED (XW2_OFFSET + 33554432u)   // 125,829,120
// ---- MID path (round-4 proven) ws layout ----
#define XW_OFFSET  25165824u
#define WS_NEEDED  (XW_OFFSET + 33554432u)     // 58,720,256

typedef __attribute__((ext_vector_type(8)))  _Float16 f16x8;
typedef __attribute__((ext_vector_type(2)))  _Float16 f16x2;
typedef __attribute__((ext_vector_type(4)))  float    f32x4;
typedef __attribute__((ext_vector_type(16))) float    f32x16;

#define MFMA16(d, va, vb) d = __builtin_amdgcn_mfma_f32_16x16x32_f16(va, vb, d, 0, 0, 0)
#define MFMA32(d, va, vb) d = __builtin_amdgcn_mfma_f32_32x32x16_f16(va, vb, d, 0, 0, 0)

// ---------- fused pre-pass: dequant W -> wf slots; cvt x -> xw slots (both XOR-pre-swizzled) ----------
__global__ void prep(const int* __restrict__ qw, const float* __restrict__ sc,
                     const float* __restrict__ zr, const float* __restrict__ x,
                     uint4* __restrict__ wf, uint4* __restrict__ xw) {
    const int WUNITS = N_DIM * KP;
    const int TOT    = WUNITS + M_DIM * KP;
    int stride = gridDim.x * blockDim.x;
    for (int i = blockIdx.x * blockDim.x + threadIdx.x; i < TOT; i += stride) {
        if (i < WUNITS) {
            int n  = i >> 9;
            int sg = i & 511;
            const int* src = qw + (size_t)n * K_DIM + sg * 8;
            int4 a = *(const int4*)src;
            int4 b = *(const int4*)(src + 4);
            int g = sg >> 4;
            float s = sc[(size_t)g * N_DIM + n];
            float z = zr[(size_t)g * N_DIM + n];
            union { _Float16 h[8]; uint4 v; } pk;
            pk.h[0]=(_Float16)((float)a.x*s+z); pk.h[1]=(_Float16)((float)a.y*s+z);
            pk.h[2]=(_Float16)((float)a.z*s+z); pk.h[3]=(_Float16)((float)a.w*s+z);
            pk.h[4]=(_Float16)((float)b.x*s+z); pk.h[5]=(_Float16)((float)b.y*s+z);
            pk.h[6]=(_Float16)((float)b.z*s+z); pk.h[7]=(_Float16)((float)b.w*s+z);
            int dst = (sg & ~7) | ((sg & 7) ^ (n & 7));
            wf[((size_t)n << 9) + dst] = pk.v;
        } else {
            int j  = i - WUNITS;
            int m  = j >> 9;
            int sg = j & 511;
            const float* src = x + ((size_t)m << 12) + sg * 8;
            float4 f0 = *(const float4*)src;
            float4 f1 = *(const float4*)(src + 4);
            union { _Float16 h[8]; uint4 v; } pk;
            pk.h[0]=(_Float16)f0.x; pk.h[1]=(_Float16)f0.y;
            pk.h[2]=(_Float16)f0.z; pk.h[3]=(_Float16)f0.w;
            pk.h[4]=(_Float16)f1.x; pk.h[5]=(_Float16)f1.y;
            pk.h[6]=(_Float16)f1.z; pk.h[7]=(_Float16)f1.w;
            int dst = (sg & ~7) | ((sg & 7) ^ (m & 7));
            xw[((size_t)m << 9) + dst] = pk.v;
        }
    }
}

// ---------- FULL main GEMM: r19 skeleton, 32x32x16 MFMA fragments ----------
__global__ __launch_bounds__(512, 2) void wq_gemm_32b(
    const uint4* __restrict__ xw,    // fp16 [M][512] slots, pre-swizzled
    const uint4* __restrict__ wf,    // fp16 [N][512] slots, pre-swizzled
    const float* __restrict__ bias,
    float*       __restrict__ out)
{
    __shared__ __align__(16) uint4 Ls[2][2][2][1024];  // [buf][op][half][unit] 128KB

    const int tid  = threadIdx.x;
    const int lane = tid & 63;
    const int wid  = tid >> 6;          // 0..7
    const int wm   = wid >> 2;          // A half 0..1
    const int wn   = wid & 3;
    const int wbh  = wn >> 1;           // B half
    const int wbl  = wn & 1;            // 64-col slice within B half
    const int l31  = lane & 31;
    const int l5   = lane >> 5;         // 0..1

    for (int q = blockIdx.x; q < NTILES; q += NWORK) {
        int swz = (q & 7) * 86 + (q >> 3);
        const int m0 = (swz & 15) * 256;
        const int n0 = (swz >> 4) * 256;

        f32x16 acc[4][2] = {};          // 4 m-frags x 2 n-frags of 32x32 (128 AGPR)

        auto stage = [&](int t, int buf, int op, int half) {
            const uint4* base = op ? (wf + (size_t)n0 * KP) : (xw + (size_t)m0 * KP);
            #pragma unroll
            for (int i = 0; i < 2; ++i) {
                int off = i * 512 + tid;
                int row = off >> 3, sl = off & 7;
                const uint4* g = base + (size_t)(half * 128 + row) * KP + t * 8 + sl;
                __builtin_amdgcn_global_load_lds(
                    (const __attribute__((address_space(1))) unsigned int*)g,
                    (__attribute__((address_space(3))) unsigned int*)&Ls[buf][op][half][off],
                    16, 0, 0);
            }
        };

        // fragments: lane reads A[row=frag*32+l31][k=(ks*16 + l5*8)..+8] (one b128)
        f16x8 a[2][4], b[2][4];
        auto lda2 = [&](int buf, int mf0) {     // 8 reads: m-frags mf0, mf0+1
            const uint4* Ab = &Ls[buf][0][wm][0];
            #pragma unroll
            for (int mi = 0; mi < 2; ++mi) {
                int r = (mf0 + mi) * 32 + l31;
                #pragma unroll
                for (int ks = 0; ks < 4; ++ks)
                    a[mi][ks] = *(const f16x8*)(Ab + r * 8 + ((ks * 2 + l5) ^ (r & 7)));
            }
        };
        auto ldb2 = [&](int buf, int nf) {      // 4 reads: n-frag nf
            const uint4* Bb = &Ls[buf][1][wbh][0];
            int r = wbl * 64 + nf * 32 + l31;
            #pragma unroll
            for (int ks = 0; ks < 4; ++ks)
                b[nf][ks] = *(const f16x8*)(Bb + r * 8 + ((ks * 2 + l5) ^ (r & 7)));
        };

#define OCT(MB, NF)                                                    \
        __builtin_amdgcn_s_setprio(1);                                 \
        _Pragma("unroll")                                              \
        for (int mi = 0; mi < 2; ++mi)                                 \
            _Pragma("unroll")                                          \
            for (int ks = 0; ks < 4; ++ks)                             \
                MFMA32(acc[MB + mi][NF], a[mi][ks], b[NF][ks]);        \
        __builtin_amdgcn_s_setprio(0);

#define BAR() __builtin_amdgcn_s_barrier()
#define VM4() asm volatile("s_waitcnt vmcnt(4)" ::: "memory")

        // ---- prologue: T0 (4 halves) + T1.B0,B1; drain T0 (keep T1.B flying) ----
        stage(0, 0, 0, 0); stage(0, 0, 0, 1); stage(0, 0, 1, 0); stage(0, 0, 1, 1);
        stage(1, 1, 1, 0); stage(1, 1, 1, 1);
        VM4();
        BAR();

        for (int it = 0; it < NT / 2; ++it) {
            const int T   = 2 * it;
            const int tp1 = T + 1;
            const int t2  = (T + 2 < NT) ? T + 2 : NT - 1;   // tail clamp: dead-region writes
            const int t3  = (T + 3 < NT) ? T + 3 : NT - 1;

            // Phase/stage/barrier structure and per-phase LDS regions are
            // byte-identical to r19 (hazard audit carries over):
            //  p0 reads A rows 0-63 + B cols 0-31; p1 B cols 32-63; p2 A rows 64-127.

            // p0: stage (T+1).A0; reads buf0 a-frags 0,1 + b-frag 0; 8 MFMA
            stage(tp1, 1, 0, 0);
            lda2(0, 0); ldb2(0, 0);
            OCT(0, 0); BAR();

            // p1: stage (T+1).A1; reads b-frag 1; 8 MFMA (buf0.B dead after)
            stage(tp1, 1, 0, 1);
            ldb2(0, 1);
            OCT(0, 1); BAR();

            // p2: stage (T+2).B0 into buf0; reads a-frags 2,3; 8 MFMA (buf0.A dead after)
            stage(t2, 0, 1, 0);
            lda2(0, 2);
            OCT(2, 1); BAR();

            // p3: stage (T+2).B1; 8 MFMA; drain keeping 2 stages -> T+1 landed
            stage(t2, 0, 1, 1);
            OCT(2, 0); VM4(); BAR();

            // p4: stage (T+2).A0; reads buf1 a-frags 0,1 + b-frag 0; 8 MFMA
            stage(t2, 0, 0, 0);
            lda2(1, 0); ldb2(1, 0);
            OCT(0, 0); BAR();

            // p5: stage (T+2).A1; reads b-frag 1; 8 MFMA
            stage(t2, 0, 0, 1);
            ldb2(1, 1);
            OCT(0, 1); BAR();

            // p6: stage (T+3).B0 into buf1; reads a-frags 2,3; 8 MFMA
            stage(t3, 1, 1, 0);
            lda2(1, 2);
            OCT(2, 1); BAR();

            // p7: stage (T+3).B1; 8 MFMA; drain -> T+2 landed
            stage(t3, 1, 1, 1);
            OCT(2, 0); VM4(); BAR();
        }

        asm volatile("s_waitcnt vmcnt(0)" ::: "memory");

        // ---- epilogue: 32x32 C/D layout col=lane&31, row=(reg&3)+8*(reg>>2)+4*(lane>>5) ----
        #pragma unroll
        for (int nf = 0; nf < 2; ++nf) {
            int col = n0 + wbh * 128 + wbl * 64 + nf * 32 + l31;
            float bv = bias[col];
            #pragma unroll
            for (int mf = 0; mf < 4; ++mf) {
                int rbase = m0 + wm * 128 + mf * 32 + 4 * l5;
                #pragma unroll
                for (int reg = 0; reg < 16; ++reg) {
                    int row = rbase + (reg & 3) + 8 * (reg >> 2);
                    out[(size_t)row * N_DIM + col] = acc[mf][nf][reg] + bv;
                }
            }
        }
        BAR();   // all waves done before next tile's staging overwrites LDS
#undef OCT
#undef BAR
#undef VM4
    }
}

// ================= MID path (round-4 proven, 471 us) =================
__global__ void pack_qw(const int* __restrict__ qw, unsigned int* __restrict__ qp) {
    int stride = gridDim.x * blockDim.x;
    for (int i = blockIdx.x * blockDim.x + threadIdx.x; i < N_DIM * KP; i += stride) {
        const int* src = qw + (size_t)i * 8;
        int4 a = *(const int4*)src;
        int4 b = *(const int4*)(src + 4);
        unsigned int w = (unsigned)a.x | ((unsigned)a.z << 4) | ((unsigned)b.x << 8) | ((unsigned)b.z << 12)
                       | ((unsigned)a.y << 16) | ((unsigned)a.w << 20) | ((unsigned)b.y << 24) | ((unsigned)b.w << 28);
        qp[i] = w;
    }
}

__global__ void cvt_x_mid(const float* __restrict__ x, uint4* __restrict__ xw) {
    int stride = gridDim.x * blockDim.x;
    for (int i = blockIdx.x * blockDim.x + threadIdx.x; i < M_DIM * KP; i += stride) {
        int m  = i >> 9;
        int sg = i & 511;
        const float* src = x + ((size_t)m << 12) + sg * 8;
        float4 f0 = *(const float4*)src;
        float4 f1 = *(const float4*)(src + 4);
        union { _Float16 h[8]; uint4 v; } pk;
        pk.h[0]=(_Float16)f0.x; pk.h[1]=(_Float16)f0.y;
        pk.h[2]=(_Float16)f0.z; pk.h[3]=(_Float16)f0.w;
        pk.h[4]=(_Float16)f1.x; pk.h[5]=(_Float16)f1.y;
        pk.h[6]=(_Float16)f1.z; pk.h[7]=(_Float16)f1.w;
        int dst = (sg & ~7) | ((sg & 7) ^ (m & 7));
        xw[((size_t)m << 9) + dst] = pk.v;
    }
}

__device__ __forceinline__ uint4 dq8m(unsigned int w, f16x2 s2, f16x2 z2) {
    const f16x2 k1024 = {(_Float16)1024.0f, (_Float16)1024.0f};
    union { f16x2 h; unsigned int u; } p0, p1, p2, p3;
    p0.u = 0x64006400u | (w & 0x000F000Fu);
    p1.u = 0x64006400u | ((w >> 4)  & 0x000F000Fu);
    p2.u = 0x64006400u | ((w >> 8)  & 0x000F000Fu);
    p3.u = 0x64006400u | ((w >> 12) & 0x000F000Fu);
    union { f16x2 h2[4]; uint4 v; } r;
    r.h2[0] = (p0.h - k1024) * s2 + z2;
    r.h2[1] = (p1.h - k1024) * s2 + z2;
    r.h2[2] = (p2.h - k1024) * s2 + z2;
    r.h2[3] = (p3.h - k1024) * s2 + z2;
    return r.v;
}

__global__ __launch_bounds__(256, 3) void wq_gemm_packed(
    const uint4*  __restrict__ xw, const uint4* __restrict__ qp4,
    const float*  __restrict__ scales, const float* __restrict__ zeros,
    const float*  __restrict__ bias, float* __restrict__ out)
{
    __shared__ __align__(16) unsigned short As[128 * 64];
    __shared__ __align__(16) unsigned short Bs[128 * 64];
    const int tid = threadIdx.x, lane = tid & 63, wid = tid >> 6;
    const int wm = wid >> 1, wn = wid & 1, l15 = lane & 15, l4 = lane >> 4;
    const int m0 = blockIdx.y * 128, n0 = blockIdx.x * 128;
    const int brow = tid >> 1, bhalf = tid & 1;
    f32x4 acc[4][4] = {};
    for (int g = 0; g < 32; ++g) {
        float s = scales[(size_t)g * N_DIM + n0 + brow];
        float z = zeros [(size_t)g * N_DIM + n0 + brow];
        f16x2 s2 = {(_Float16)s, (_Float16)s};
        f16x2 z2 = {(_Float16)z, (_Float16)z};
        #pragma unroll
        for (int half = 0; half < 2; ++half) {
            const int kt = g * 2 + half;
            #pragma unroll
            for (int i = 0; i < 4; ++i) {
                int off16 = i * 256 + tid;
                int row = off16 >> 3, sl = off16 & 7;
                const uint4* gsrc = xw + (size_t)(m0 + row) * KP + kt * 8 + sl;
                __builtin_amdgcn_global_load_lds(
                    (const __attribute__((address_space(1))) unsigned int*)gsrc,
                    (__attribute__((address_space(3))) unsigned int*)((char*)As + off16 * 16),
                    16, 0, 0);
            }
            uint4 qword = qp4[(size_t)(n0 + brow) * 128 + kt * 2 + bhalf];
            #pragma unroll
            for (int j = 0; j < 4; ++j) {
                unsigned int w = (j == 0) ? qword.x : (j == 1) ? qword.y : (j == 2) ? qword.z : qword.w;
                int sl = (bhalf * 4 + j) ^ (brow & 7);
                *(uint4*)((char*)Bs + brow * 128 + sl * 16) = dq8m(w, s2, z2);
            }
            __syncthreads();
            #pragma unroll
            for (int ks = 0; ks < 2; ++ks) {
                f16x8 a[4], b[4];
                #pragma unroll
                for (int m = 0; m < 4; ++m) {
                    int row = wm * 64 + m * 16 + l15;
                    int sl  = (ks * 4 + l4) ^ (row & 7);
                    a[m] = *(const f16x8*)((char*)As + row * 128 + sl * 16);
                }
                #pragma unroll
                for (int n = 0; n < 4; ++n) {
                    int row = wn * 64 + n * 16 + l15;
                    int sl  = (ks * 4 + l4) ^ (row & 7);
                    b[n] = *(const f16x8*)((char*)Bs + row * 128 + sl * 16);
                }
                #pragma unroll
                for (int m = 0; m < 4; ++m)
                    #pragma unroll
                    for (int n = 0; n < 4; ++n)
                        MFMA16(acc[m][n], a[m], b[n]);
            }
            __syncthreads();
        }
    }
    #pragma unroll
    for (int n = 0; n < 4; ++n) {
        int col = n0 + wn * 64 + n * 16 + l15;
        float bv = bias[col];
        #pragma unroll
        for (int m = 0; m < 4; ++m) {
            int rbase = m0 + wm * 64 + m * 16 + l4 * 4;
            #pragma unroll
            for (int j = 0; j < 4; ++j)
                out[(size_t)(rbase + j) * N_DIM + col] = acc[m][n][j] + bv;
        }
    }
}

extern "C" void kernel_launch(void* const* d_in, const int* in_sizes, int n_in,
                              void* d_out, int out_size, void* d_ws, size_t ws_size,
                              hipStream_t stream) {
    const float* x  = (const float*)d_in[0];
    const int*   qw = (const int*)d_in[1];
    const float* sc = (const float*)d_in[2];
    const float* zr = (const float*)d_in[3];
    const float* bi = (const float*)d_in[4];
    float* o = (float*)d_out;

    if (ws_size >= FULL_NEEDED) {
        uint4* wf = (uint4*)d_ws;
        uint4* xw = (uint4*)((char*)d_ws + XW2_OFFSET);
        prep<<<3072, 256, 0, stream>>>(qw, sc, zr, x, wf, xw);
        wq_gemm_32b<<<dim3(NWORK), dim3(512), 0, stream>>>(xw, wf, bi, o);
    } else {
        unsigned int* qp = (unsigned int*)d_ws;
        uint4* xw = (uint4*)((char*)d_ws + XW_OFFSET);
        pack_qw <<<2048, 256, 0, stream>>>(qw, qp);
        cvt_x_mid<<<2048, 256, 0, stream>>>(x, xw);
        dim3 grid(N_DIM / 128, M_DIM / 128);
        wq_gemm_packed<<<grid, dim3(256), 0, stream>>>((const uint4*)xw, (const uint4*)qp, sc, zr, bi, o);
    }
}

// Round 24
// 407.650 us; speedup vs baseline: 1.0692x; 1.0692x over previous
//
#include <hip/hip_runtime.h>
#include <stdint.h>

#define M_DIM 4096
#define K_DIM 4096
#define N_DIM 11008
#define KP    512              // 16B slots (8 fp16) per K row
#define NT    64               // K tiles of 64
#define NTILES 688             // 16 x 43 output tiles of 256x256
#define NWORK  512             // persistent blocks

// ---- FULL path ws layout: Wf fp16 [N][K] + xw fp16 [M][K] ----
#define XW2_OFFSET  92274688u
#define FULL_NEEDED (XW2_OFFSET + 33554432u)   // 125,829,120
// ---- MID path (round-4 proven) ws layout ----
#define XW_OFFSET  25165824u
#define WS_NEEDED  (XW_OFFSET + 33554432u)     // 58,720,256

typedef __attribute__((ext_vector_type(8))) _Float16 f16x8;
typedef __attribute__((ext_vector_type(2))) _Float16 f16x2;
typedef __attribute__((ext_vector_type(4))) float    f32x4;

#define MFMA16(d, va, vb) d = __builtin_amdgcn_mfma_f32_16x16x32_f16(va, vb, d, 0, 0, 0)

// ---------- fused pre-pass: dequant W -> wf slots; cvt x -> xw slots (both XOR-pre-swizzled) ----------
__global__ void prep(const int* __restrict__ qw, const float* __restrict__ sc,
                     const float* __restrict__ zr, const float* __restrict__ x,
                     uint4* __restrict__ wf, uint4* __restrict__ xw) {
    const int WUNITS = N_DIM * KP;
    const int TOT    = WUNITS + M_DIM * KP;
    int stride = gridDim.x * blockDim.x;
    for (int i = blockIdx.x * blockDim.x + threadIdx.x; i < TOT; i += stride) {
        if (i < WUNITS) {
            int n  = i >> 9;
            int sg = i & 511;
            const int* src = qw + (size_t)n * K_DIM + sg * 8;
            int4 a = *(const int4*)src;
            int4 b = *(const int4*)(src + 4);
            int g = sg >> 4;
            float s = sc[(size_t)g * N_DIM + n];
            float z = zr[(size_t)g * N_DIM + n];
            union { _Float16 h[8]; uint4 v; } pk;
            pk.h[0]=(_Float16)((float)a.x*s+z); pk.h[1]=(_Float16)((float)a.y*s+z);
            pk.h[2]=(_Float16)((float)a.z*s+z); pk.h[3]=(_Float16)((float)a.w*s+z);
            pk.h[4]=(_Float16)((float)b.x*s+z); pk.h[5]=(_Float16)((float)b.y*s+z);
            pk.h[6]=(_Float16)((float)b.z*s+z); pk.h[7]=(_Float16)((float)b.w*s+z);
            int dst = (sg & ~7) | ((sg & 7) ^ (n & 7));
            wf[((size_t)n << 9) + dst] = pk.v;
        } else {
            int j  = i - WUNITS;
            int m  = j >> 9;
            int sg = j & 511;
            const float* src = x + ((size_t)m << 12) + sg * 8;
            float4 f0 = *(const float4*)src;
            float4 f1 = *(const float4*)(src + 4);
            union { _Float16 h[8]; uint4 v; } pk;
            pk.h[0]=(_Float16)f0.x; pk.h[1]=(_Float16)f0.y;
            pk.h[2]=(_Float16)f0.z; pk.h[3]=(_Float16)f0.w;
            pk.h[4]=(_Float16)f1.x; pk.h[5]=(_Float16)f1.y;
            pk.h[6]=(_Float16)f1.z; pk.h[7]=(_Float16)f1.w;
            int dst = (sg & ~7) | ((sg & 7) ^ (m & 7));
            xw[((size_t)m << 9) + dst] = pk.v;
        }
    }
}

// ---------- FULL main GEMM: persistent, 256x256, 8 waves, 8-phase, ONE barrier/phase ----------
__global__ __launch_bounds__(512, 2) void wq_gemm_8p1b(
    const uint4* __restrict__ xw,    // fp16 [M][512] slots, pre-swizzled
    const uint4* __restrict__ wf,    // fp16 [N][512] slots, pre-swizzled
    const float* __restrict__ bias,
    float*       __restrict__ out)
{
    __shared__ __align__(16) uint4 Ls[2][2][2][1024];  // [buf][op][half][unit] 128KB

    const int tid  = threadIdx.x;
    const int lane = tid & 63;
    const int wid  = tid >> 6;          // 0..7
    const int wm   = wid >> 2;          // A half 0..1
    const int wn   = wid & 3;
    const int wbh  = wn >> 1;           // B half
    const int wbl  = wn & 1;            // 64-col slice within B half
    const int l15  = lane & 15;
    const int l4   = lane >> 4;

    for (int q = blockIdx.x; q < NTILES; q += NWORK) {
        // XCD-aware bijective swizzle on tile index
        int swz = (q & 7) * 86 + (q >> 3);
        const int m0 = (swz & 15) * 256;    // 16 m-blocks
        const int n0 = (swz >> 4) * 256;    // 43 n-blocks

        f32x4 acc[8][4] = {};

        auto stage = [&](int t, int buf, int op, int half) {
            const uint4* base = op ? (wf + (size_t)n0 * KP) : (xw + (size_t)m0 * KP);
            #pragma unroll
            for (int i = 0; i < 2; ++i) {
                int off = i * 512 + tid;            // 0..1023
                int row = off >> 3, sl = off & 7;
                const uint4* g = base + (size_t)(half * 128 + row) * KP + t * 8 + sl;
                __builtin_amdgcn_global_load_lds(
                    (const __attribute__((address_space(1))) unsigned int*)g,
                    (__attribute__((address_space(3))) unsigned int*)&Ls[buf][op][half][off],
                    16, 0, 0);
            }
        };

        f16x8 a[4][2], b[4][2];
        auto lda = [&](int buf, int mbase) {            // 8 ds_reads: a[0..3]
            const uint4* Ab = &Ls[buf][0][wm][0];
            #pragma unroll
            for (int mf = 0; mf < 4; ++mf) {
                int r = mbase + mf * 16 + l15;
                a[mf][0] = *(const f16x8*)(Ab + r * 8 + ((0 + l4) ^ (r & 7)));
                a[mf][1] = *(const f16x8*)(Ab + r * 8 + ((4 + l4) ^ (r & 7)));
            }
        };
        auto ldb = [&](int buf, int nf0) {              // 4 ds_reads: b[nf0..nf0+1]
            const uint4* Bb = &Ls[buf][1][wbh][0];
            #pragma unroll
            for (int nf = 0; nf < 2; ++nf) {
                int r = wbl * 64 + (nf0 + nf) * 16 + l15;
                b[nf0 + nf][0] = *(const f16x8*)(Bb + r * 8 + ((0 + l4) ^ (r & 7)));
                b[nf0 + nf][1] = *(const f16x8*)(Bb + r * 8 + ((4 + l4) ^ (r & 7)));
            }
        };

#define QUAD(MB, NB)                                                   \
        __builtin_amdgcn_s_setprio(1);                                 \
        _Pragma("unroll")                                              \
        for (int mf = 0; mf < 4; ++mf)                                 \
            _Pragma("unroll")                                          \
            for (int nf = 0; nf < 2; ++nf) {                           \
                MFMA16(acc[MB + mf][NB + nf], a[mf][0], b[NB + nf][0]);\
                MFMA16(acc[MB + mf][NB + nf], a[mf][1], b[NB + nf][1]);\
            }                                                          \
        __builtin_amdgcn_s_setprio(0);

#define BAR() __builtin_amdgcn_s_barrier()
#define VM4() asm volatile("s_waitcnt vmcnt(4)" ::: "memory")

        // ---- prologue: T0 (4 halves) + T1.B0,B1; drain T0 (keep T1.B flying) ----
        stage(0, 0, 0, 0); stage(0, 0, 0, 1); stage(0, 0, 1, 0); stage(0, 0, 1, 1);
        stage(1, 1, 1, 0); stage(1, 1, 1, 1);
        VM4();                                  // T0's 8 loads landed; T1.B's 4 in flight
        BAR();

        for (int it = 0; it < NT / 2; ++it) {
            const int T   = 2 * it;
            const int tp1 = T + 1;
            const int t2  = (T + 2 < NT) ? T + 2 : NT - 1;   // tail clamp: dead-region writes
            const int t3  = (T + 3 < NT) ? T + 3 : NT - 1;

            // One barrier per phase (end only): waves desync within the phase ->
            // LDS-read segment of late waves overlaps MFMA of early waves.
            // Race-audit: every stage target's last reader is >=1 collective
            // barrier earlier (A-stages: >=3; B-stages: 1). vmcnt publish = VM4+BAR.

            // p0: stage (T+1).A0; reads buf0 a(0-63)+b01; MFMA Q00
            stage(tp1, 1, 0, 0);
            lda(0, 0); ldb(0, 0);
            QUAD(0, 0); BAR();

            // p1: stage (T+1).A1; reads b23; MFMA Q02 (buf0.B dead after)
            stage(tp1, 1, 0, 1);
            ldb(0, 2);
            QUAD(0, 2); BAR();

            // p2: stage (T+2).B0 into buf0; reads a(64-127); MFMA Q42 (buf0.A dead after)
            stage(t2, 0, 1, 0);
            lda(0, 64);
            QUAD(4, 2); BAR();

            // p3: stage (T+2).B1; MFMA Q40; drain keeping 2 stages -> T+1 landed
            stage(t2, 0, 1, 1);
            QUAD(4, 0); VM4(); BAR();

            // p4: stage (T+2).A0; reads buf1 a(0-63)+b01; MFMA Q00
            stage(t2, 0, 0, 0);
            lda(1, 0); ldb(1, 0);
            QUAD(0, 0); BAR();

            // p5: stage (T+2).A1; reads b23; MFMA Q02
            stage(t2, 0, 0, 1);
            ldb(1, 2);
            QUAD(0, 2); BAR();

            // p6: stage (T+3).B0 into buf1; reads a(64-127); MFMA Q42
            stage(t3, 1, 1, 0);
            lda(1, 64);
            QUAD(4, 2); BAR();

            // p7: stage (T+3).B1; MFMA Q40; drain -> T+2 landed
            stage(t3, 1, 1, 1);
            QUAD(4, 0); VM4(); BAR();
        }

        asm volatile("s_waitcnt vmcnt(0)" ::: "memory");   // drain (0 outstanding at next prologue)

        // ---- epilogue ----
        #pragma unroll
        for (int nf = 0; nf < 4; ++nf) {
            int col = n0 + wbh * 128 + wbl * 64 + nf * 16 + l15;
            float bv = bias[col];
            #pragma unroll
            for (int mf = 0; mf < 8; ++mf) {
                int rbase = m0 + wm * 128 + mf * 16 + l4 * 4;
                #pragma unroll
                for (int j = 0; j < 4; ++j)
                    out[(size_t)(rbase + j) * N_DIM + col] = acc[mf][nf][j] + bv;
            }
        }
        BAR();   // all waves done with epilogue before next tile's staging overwrites LDS
#undef QUAD
#undef BAR
#undef VM4
    }
}

// ================= MID path (round-4 proven, 471 us) =================
__global__ void pack_qw(const int* __restrict__ qw, unsigned int* __restrict__ qp) {
    int stride = gridDim.x * blockDim.x;
    for (int i = blockIdx.x * blockDim.x + threadIdx.x; i < N_DIM * KP; i += stride) {
        const int* src = qw + (size_t)i * 8;
        int4 a = *(const int4*)src;
        int4 b = *(const int4*)(src + 4);
        unsigned int w = (unsigned)a.x | ((unsigned)a.z << 4) | ((unsigned)b.x << 8) | ((unsigned)b.z << 12)
                       | ((unsigned)a.y << 16) | ((unsigned)a.w << 20) | ((unsigned)b.y << 24) | ((unsigned)b.w << 28);
        qp[i] = w;
    }
}

__global__ void cvt_x_mid(const float* __restrict__ x, uint4* __restrict__ xw) {
    int stride = gridDim.x * blockDim.x;
    for (int i = blockIdx.x * blockDim.x + threadIdx.x; i < M_DIM * KP; i += stride) {
        int m  = i >> 9;
        int sg = i & 511;
        const float* src = x + ((size_t)m << 12) + sg * 8;
        float4 f0 = *(const float4*)src;
        float4 f1 = *(const float4*)(src + 4);
        union { _Float16 h[8]; uint4 v; } pk;
        pk.h[0]=(_Float16)f0.x; pk.h[1]=(_Float16)f0.y;
        pk.h[2]=(_Float16)f0.z; pk.h[3]=(_Float16)f0.w;
        pk.h[4]=(_Float16)f1.x; pk.h[5]=(_Float16)f1.y;
        pk.h[6]=(_Float16)f1.z; pk.h[7]=(_Float16)f1.w;
        int dst = (sg & ~7) | ((sg & 7) ^ (m & 7));
        xw[((size_t)m << 9) + dst] = pk.v;
    }
}

__device__ __forceinline__ uint4 dq8m(unsigned int w, f16x2 s2, f16x2 z2) {
    const f16x2 k1024 = {(_Float16)1024.0f, (_Float16)1024.0f};
    union { f16x2 h; unsigned int u; } p0, p1, p2, p3;
    p0.u = 0x64006400u | (w & 0x000F000Fu);
    p1.u = 0x64006400u | ((w >> 4)  & 0x000F000Fu);
    p2.u = 0x64006400u | ((w >> 8)  & 0x000F000Fu);
    p3.u = 0x64006400u | ((w >> 12) & 0x000F000Fu);
    union { f16x2 h2[4]; uint4 v; } r;
    r.h2[0] = (p0.h - k1024) * s2 + z2;
    r.h2[1] = (p1.h - k1024) * s2 + z2;
    r.h2[2] = (p2.h - k1024) * s2 + z2;
    r.h2[3] = (p3.h - k1024) * s2 + z2;
    return r.v;
}

__global__ __launch_bounds__(256, 3) void wq_gemm_packed(
    const uint4*  __restrict__ xw, const uint4* __restrict__ qp4,
    const float*  __restrict__ scales, const float* __restrict__ zeros,
    const float*  __restrict__ bias, float* __restrict__ out)
{
    __shared__ __align__(16) unsigned short As[128 * 64];
    __shared__ __align__(16) unsigned short Bs[128 * 64];
    const int tid = threadIdx.x, lane = tid & 63, wid = tid >> 6;
    const int wm = wid >> 1, wn = wid & 1, l15 = lane & 15, l4 = lane >> 4;
    const int m0 = blockIdx.y * 128, n0 = blockIdx.x * 128;
    const int brow = tid >> 1, bhalf = tid & 1;
    f32x4 acc[4][4] = {};
    for (int g = 0; g < 32; ++g) {
        float s = scales[(size_t)g * N_DIM + n0 + brow];
        float z = zeros [(size_t)g * N_DIM + n0 + brow];
        f16x2 s2 = {(_Float16)s, (_Float16)s};
        f16x2 z2 = {(_Float16)z, (_Float16)z};
        #pragma unroll
        for (int half = 0; half < 2; ++half) {
            const int kt = g * 2 + half;
            #pragma unroll
            for (int i = 0; i < 4; ++i) {
                int off16 = i * 256 + tid;
                int row = off16 >> 3, sl = off16 & 7;
                const uint4* gsrc = xw + (size_t)(m0 + row) * KP + kt * 8 + sl;
                __builtin_amdgcn_global_load_lds(
                    (const __attribute__((address_space(1))) unsigned int*)gsrc,
                    (__attribute__((address_space(3))) unsigned int*)((char*)As + off16 * 16),
                    16, 0, 0);
            }
            uint4 qword = qp4[(size_t)(n0 + brow) * 128 + kt * 2 + bhalf];
            #pragma unroll
            for (int j = 0; j < 4; ++j) {
                unsigned int w = (j == 0) ? qword.x : (j == 1) ? qword.y : (j == 2) ? qword.z : qword.w;
                int sl = (bhalf * 4 + j) ^ (brow & 7);
                *(uint4*)((char*)Bs + brow * 128 + sl * 16) = dq8m(w, s2, z2);
            }
            __syncthreads();
            #pragma unroll
            for (int ks = 0; ks < 2; ++ks) {
                f16x8 a[4], b[4];
                #pragma unroll
                for (int m = 0; m < 4; ++m) {
                    int row = wm * 64 + m * 16 + l15;
                    int sl  = (ks * 4 + l4) ^ (row & 7);
                    a[m] = *(const f16x8*)((char*)As + row * 128 + sl * 16);
                }
                #pragma unroll
                for (int n = 0; n < 4; ++n) {
                    int row = wn * 64 + n * 16 + l15;
                    int sl  = (ks * 4 + l4) ^ (row & 7);
                    b[n] = *(const f16x8*)((char*)Bs + row * 128 + sl * 16);
                }
                #pragma unroll
                for (int m = 0; m < 4; ++m)
                    #pragma unroll
                    for (int n = 0; n < 4; ++n)
                        MFMA16(acc[m][n], a[m], b[n]);
            }
            __syncthreads();
        }
    }
    #pragma unroll
    for (int n = 0; n < 4; ++n) {
        int col = n0 + wn * 64 + n * 16 + l15;
        float bv = bias[col];
        #pragma unroll
        for (int m = 0; m < 4; ++m) {
            int rbase = m0 + wm * 64 + m * 16 + l4 * 4;
            #pragma unroll
            for (int j = 0; j < 4; ++j)
                out[(size_t)(rbase + j) * N_DIM + col] = acc[m][n][j] + bv;
        }
    }
}

extern "C" void kernel_launch(void* const* d_in, const int* in_sizes, int n_in,
                              void* d_out, int out_size, void* d_ws, size_t ws_size,
                              hipStream_t stream) {
    const float* x  = (const float*)d_in[0];
    const int*   qw = (const int*)d_in[1];
    const float* sc = (const float*)d_in[2];
    const float* zr = (const float*)d_in[3];
    const float* bi = (const float*)d_in[4];
    float* o = (float*)d_out;

    if (ws_size >= FULL_NEEDED) {
        uint4* wf = (uint4*)d_ws;
        uint4* xw = (uint4*)((char*)d_ws + XW2_OFFSET);
        prep<<<3072, 256, 0, stream>>>(qw, sc, zr, x, wf, xw);
        wq_gemm_8p1b<<<dim3(NWORK), dim3(512), 0, stream>>>(xw, wf, bi, o);
    } else {
        unsigned int* qp = (unsigned int*)d_ws;
        uint4* xw = (uint4*)((char*)d_ws + XW_OFFSET);
        pack_qw <<<2048, 256, 0, stream>>>(qw, qp);
        cvt_x_mid<<<2048, 256, 0, stream>>>(x, xw);
        dim3 grid(N_DIM / 128, M_DIM / 128);
        wq_gemm_packed<<<grid, dim3(256), 0, stream>>>((const uint4*)xw, (const uint4*)qp, sc, zr, bi, o);
    }
}

// Round 25
// 406.158 us; speedup vs baseline: 1.0731x; 1.0037x over previous
//
#include <hip/hip_runtime.h>
#include <stdint.h>

#define M_DIM 4096
#define K_DIM 4096
#define N_DIM 11008
#define KP    512              // 16B slots (8 fp16) per K row
#define NT    64               // K tiles of 64
#define NTILES 688             // 16 x 43 output tiles of 256x256
#define NWORK  512             // persistent blocks

// ---- FULL path ws layout: Wf fp16 [N][K] + xw fp16 [M][K] ----
#define XW2_OFFSET  92274688u
#define FULL_NEEDED (XW2_OFFSET + 33554432u)   // 125,829,120
// ---- MID path (round-4 proven) ws layout ----
#define XW_OFFSET  25165824u
#define WS_NEEDED  (XW_OFFSET + 33554432u)     // 58,720,256

typedef __attribute__((ext_vector_type(8))) _Float16 f16x8;
typedef __attribute__((ext_vector_type(2))) _Float16 f16x2;
typedef __attribute__((ext_vector_type(4))) float    f32x4;

#define MFMA16(d, va, vb) d = __builtin_amdgcn_mfma_f32_16x16x32_f16(va, vb, d, 0, 0, 0)

// ---------- fused pre-pass: dequant W -> wf slots; cvt x -> xw slots (both XOR-pre-swizzled) ----------
__global__ void prep(const int* __restrict__ qw, const float* __restrict__ sc,
                     const float* __restrict__ zr, const float* __restrict__ x,
                     uint4* __restrict__ wf, uint4* __restrict__ xw) {
    const int WUNITS = N_DIM * KP;
    const int TOT    = WUNITS + M_DIM * KP;
    int stride = gridDim.x * blockDim.x;
    for (int i = blockIdx.x * blockDim.x + threadIdx.x; i < TOT; i += stride) {
        if (i < WUNITS) {
            int n  = i >> 9;
            int sg = i & 511;
            const int* src = qw + (size_t)n * K_DIM + sg * 8;
            int4 a = *(const int4*)src;
            int4 b = *(const int4*)(src + 4);
            int g = sg >> 4;
            float s = sc[(size_t)g * N_DIM + n];
            float z = zr[(size_t)g * N_DIM + n];
            union { _Float16 h[8]; uint4 v; } pk;
            pk.h[0]=(_Float16)((float)a.x*s+z); pk.h[1]=(_Float16)((float)a.y*s+z);
            pk.h[2]=(_Float16)((float)a.z*s+z); pk.h[3]=(_Float16)((float)a.w*s+z);
            pk.h[4]=(_Float16)((float)b.x*s+z); pk.h[5]=(_Float16)((float)b.y*s+z);
            pk.h[6]=(_Float16)((float)b.z*s+z); pk.h[7]=(_Float16)((float)b.w*s+z);
            int dst = (sg & ~7) | ((sg & 7) ^ (n & 7));
            wf[((size_t)n << 9) + dst] = pk.v;
        } else {
            int j  = i - WUNITS;
            int m  = j >> 9;
            int sg = j & 511;
            const float* src = x + ((size_t)m << 12) + sg * 8;
            float4 f0 = *(const float4*)src;
            float4 f1 = *(const float4*)(src + 4);
            union { _Float16 h[8]; uint4 v; } pk;
            pk.h[0]=(_Float16)f0.x; pk.h[1]=(_Float16)f0.y;
            pk.h[2]=(_Float16)f0.z; pk.h[3]=(_Float16)f0.w;
            pk.h[4]=(_Float16)f1.x; pk.h[5]=(_Float16)f1.y;
            pk.h[6]=(_Float16)f1.z; pk.h[7]=(_Float16)f1.w;
            int dst = (sg & ~7) | ((sg & 7) ^ (m & 7));
            xw[((size_t)m << 9) + dst] = pk.v;
        }
    }
}

// ---------- FULL main GEMM: persistent, 256x256, 8 waves, 8-phase, ONE barrier/phase ----------
__global__ __launch_bounds__(512, 2) void wq_gemm_8p1b(
    const uint4* __restrict__ xw,    // fp16 [M][512] slots, pre-swizzled
    const uint4* __restrict__ wf,    // fp16 [N][512] slots, pre-swizzled
    const float* __restrict__ bias,
    float*       __restrict__ out)
{
    __shared__ __align__(16) uint4 Ls[2][2][2][1024];  // [buf][op][half][unit] 128KB

    const int tid  = threadIdx.x;
    const int lane = tid & 63;
    const int wid  = tid >> 6;          // 0..7
    const int wm   = wid >> 2;          // A half 0..1
    const int wn   = wid & 3;
    const int wbh  = wn >> 1;           // B half
    const int wbl  = wn & 1;            // 64-col slice within B half
    const int l15  = lane & 15;
    const int l4   = lane >> 4;

    for (int q = blockIdx.x; q < NTILES; q += NWORK) {
        // XCD-aware bijective swizzle on tile index
        int swz = (q & 7) * 86 + (q >> 3);
        const int m0 = (swz & 15) * 256;    // 16 m-blocks
        const int n0 = (swz >> 4) * 256;    // 43 n-blocks

        f32x4 acc[8][4] = {};

        auto stage = [&](int t, int buf, int op, int half) {
            const uint4* base = op ? (wf + (size_t)n0 * KP) : (xw + (size_t)m0 * KP);
            #pragma unroll
            for (int i = 0; i < 2; ++i) {
                int off = i * 512 + tid;            // 0..1023
                int row = off >> 3, sl = off & 7;
                const uint4* g = base + (size_t)(half * 128 + row) * KP + t * 8 + sl;
                __builtin_amdgcn_global_load_lds(
                    (const __attribute__((address_space(1))) unsigned int*)g,
                    (__attribute__((address_space(3))) unsigned int*)&Ls[buf][op][half][off],
                    16, 0, 0);
            }
        };

        f16x8 a[4][2], b[4][2];
        auto lda = [&](int buf, int mbase) {            // 8 ds_reads: a[0..3]
            const uint4* Ab = &Ls[buf][0][wm][0];
            #pragma unroll
            for (int mf = 0; mf < 4; ++mf) {
                int r = mbase + mf * 16 + l15;
                a[mf][0] = *(const f16x8*)(Ab + r * 8 + ((0 + l4) ^ (r & 7)));
                a[mf][1] = *(const f16x8*)(Ab + r * 8 + ((4 + l4) ^ (r & 7)));
            }
        };
        auto ldb = [&](int buf, int nf0) {              // 4 ds_reads: b[nf0..nf0+1]
            const uint4* Bb = &Ls[buf][1][wbh][0];
            #pragma unroll
            for (int nf = 0; nf < 2; ++nf) {
                int r = wbl * 64 + (nf0 + nf) * 16 + l15;
                b[nf0 + nf][0] = *(const f16x8*)(Bb + r * 8 + ((0 + l4) ^ (r & 7)));
                b[nf0 + nf][1] = *(const f16x8*)(Bb + r * 8 + ((4 + l4) ^ (r & 7)));
            }
        };

#define QUAD(MB, NB)                                                   \
        __builtin_amdgcn_s_setprio(1);                                 \
        _Pragma("unroll")                                              \
        for (int mf = 0; mf < 4; ++mf)                                 \
            _Pragma("unroll")                                          \
            for (int nf = 0; nf < 2; ++nf) {                           \
                MFMA16(acc[MB + mf][NB + nf], a[mf][0], b[NB + nf][0]);\
                MFMA16(acc[MB + mf][NB + nf], a[mf][1], b[NB + nf][1]);\
            }                                                          \
        __builtin_amdgcn_s_setprio(0);

#define BAR() __builtin_amdgcn_s_barrier()
#define VM4() asm volatile("s_waitcnt vmcnt(4)" ::: "memory")

        // ---- prologue: T0 (4 halves) + T1.B0,B1; drain T0 (keep T1.B flying) ----
        stage(0, 0, 0, 0); stage(0, 0, 0, 1); stage(0, 0, 1, 0); stage(0, 0, 1, 1);
        stage(1, 1, 1, 0); stage(1, 1, 1, 1);
        VM4();                                  // T0's 8 loads landed; T1.B's 4 in flight
        BAR();

        for (int it = 0; it < NT / 2; ++it) {
            const int T   = 2 * it;
            const int tp1 = T + 1;
            const int t2  = (T + 2 < NT) ? T + 2 : NT - 1;   // tail clamp: dead-region writes
            const int t3  = (T + 3 < NT) ? T + 3 : NT - 1;

            // One barrier per phase (end only): waves desync within the phase ->
            // LDS-read segment of late waves overlaps MFMA of early waves.
            // Race-audit: every stage target's last reader is >=1 collective
            // barrier earlier (A-stages: >=3; B-stages: 1). vmcnt publish = VM4+BAR.

            // p0: stage (T+1).A0; reads buf0 a(0-63)+b01; MFMA Q00
            stage(tp1, 1, 0, 0);
            lda(0, 0); ldb(0, 0);
            QUAD(0, 0); BAR();

            // p1: stage (T+1).A1; reads b23; MFMA Q02 (buf0.B dead after)
            stage(tp1, 1, 0, 1);
            ldb(0, 2);
            QUAD(0, 2); BAR();

            // p2: stage (T+2).B0 into buf0; reads a(64-127); MFMA Q42 (buf0.A dead after)
            stage(t2, 0, 1, 0);
            lda(0, 64);
            QUAD(4, 2); BAR();

            // p3: stage (T+2).B1; MFMA Q40; drain keeping 2 stages -> T+1 landed
            stage(t2, 0, 1, 1);
            QUAD(4, 0); VM4(); BAR();

            // p4: stage (T+2).A0; reads buf1 a(0-63)+b01; MFMA Q00
            stage(t2, 0, 0, 0);
            lda(1, 0); ldb(1, 0);
            QUAD(0, 0); BAR();

            // p5: stage (T+2).A1; reads b23; MFMA Q02
            stage(t2, 0, 0, 1);
            ldb(1, 2);
            QUAD(0, 2); BAR();

            // p6: stage (T+3).B0 into buf1; reads a(64-127); MFMA Q42
            stage(t3, 1, 1, 0);
            lda(1, 64);
            QUAD(4, 2); BAR();

            // p7: stage (T+3).B1; MFMA Q40; drain -> T+2 landed
            stage(t3, 1, 1, 1);
            QUAD(4, 0); VM4(); BAR();
        }

        asm volatile("s_waitcnt vmcnt(0)" ::: "memory");   // drain (0 outstanding at next prologue)

        // ---- epilogue ----
        #pragma unroll
        for (int nf = 0; nf < 4; ++nf) {
            int col = n0 + wbh * 128 + wbl * 64 + nf * 16 + l15;
            float bv = bias[col];
            #pragma unroll
            for (int mf = 0; mf < 8; ++mf) {
                int rbase = m0 + wm * 128 + mf * 16 + l4 * 4;
                #pragma unroll
                for (int j = 0; j < 4; ++j)
                    out[(size_t)(rbase + j) * N_DIM + col] = acc[mf][nf][j] + bv;
            }
        }
        BAR();   // all waves done with epilogue before next tile's staging overwrites LDS
#undef QUAD
#undef BAR
#undef VM4
    }
}

// ================= MID path (round-4 proven, 471 us) =================
__global__ void pack_qw(const int* __restrict__ qw, unsigned int* __restrict__ qp) {
    int stride = gridDim.x * blockDim.x;
    for (int i = blockIdx.x * blockDim.x + threadIdx.x; i < N_DIM * KP; i += stride) {
        const int* src = qw + (size_t)i * 8;
        int4 a = *(const int4*)src;
        int4 b = *(const int4*)(src + 4);
        unsigned int w = (unsigned)a.x | ((unsigned)a.z << 4) | ((unsigned)b.x << 8) | ((unsigned)b.z << 12)
                       | ((unsigned)a.y << 16) | ((unsigned)a.w << 20) | ((unsigned)b.y << 24) | ((unsigned)b.w << 28);
        qp[i] = w;
    }
}

__global__ void cvt_x_mid(const float* __restrict__ x, uint4* __restrict__ xw) {
    int stride = gridDim.x * blockDim.x;
    for (int i = blockIdx.x * blockDim.x + threadIdx.x; i < M_DIM * KP; i += stride) {
        int m  = i >> 9;
        int sg = i & 511;
        const float* src = x + ((size_t)m << 12) + sg * 8;
        float4 f0 = *(const float4*)src;
        float4 f1 = *(const float4*)(src + 4);
        union { _Float16 h[8]; uint4 v; } pk;
        pk.h[0]=(_Float16)f0.x; pk.h[1]=(_Float16)f0.y;
        pk.h[2]=(_Float16)f0.z; pk.h[3]=(_Float16)f0.w;
        pk.h[4]=(_Float16)f1.x; pk.h[5]=(_Float16)f1.y;
        pk.h[6]=(_Float16)f1.z; pk.h[7]=(_Float16)f1.w;
        int dst = (sg & ~7) | ((sg & 7) ^ (m & 7));
        xw[((size_t)m << 9) + dst] = pk.v;
    }
}

__device__ __forceinline__ uint4 dq8m(unsigned int w, f16x2 s2, f16x2 z2) {
    const f16x2 k1024 = {(_Float16)1024.0f, (_Float16)1024.0f};
    union { f16x2 h; unsigned int u; } p0, p1, p2, p3;
    p0.u = 0x64006400u | (w & 0x000F000Fu);
    p1.u = 0x64006400u | ((w >> 4)  & 0x000F000Fu);
    p2.u = 0x64006400u | ((w >> 8)  & 0x000F000Fu);
    p3.u = 0x64006400u | ((w >> 12) & 0x000F000Fu);
    union { f16x2 h2[4]; uint4 v; } r;
    r.h2[0] = (p0.h - k1024) * s2 + z2;
    r.h2[1] = (p1.h - k1024) * s2 + z2;
    r.h2[2] = (p2.h - k1024) * s2 + z2;
    r.h2[3] = (p3.h - k1024) * s2 + z2;
    return r.v;
}

__global__ __launch_bounds__(256, 3) void wq_gemm_packed(
    const uint4*  __restrict__ xw, const uint4* __restrict__ qp4,
    const float*  __restrict__ scales, const float* __restrict__ zeros,
    const float*  __restrict__ bias, float* __restrict__ out)
{
    __shared__ __align__(16) unsigned short As[128 * 64];
    __shared__ __align__(16) unsigned short Bs[128 * 64];
    const int tid = threadIdx.x, lane = tid & 63, wid = tid >> 6;
    const int wm = wid >> 1, wn = wid & 1, l15 = lane & 15, l4 = lane >> 4;
    const int m0 = blockIdx.y * 128, n0 = blockIdx.x * 128;
    const int brow = tid >> 1, bhalf = tid & 1;
    f32x4 acc[4][4] = {};
    for (int g = 0; g < 32; ++g) {
        float s = scales[(size_t)g * N_DIM + n0 + brow];
        float z = zeros [(size_t)g * N_DIM + n0 + brow];
        f16x2 s2 = {(_Float16)s, (_Float16)s};
        f16x2 z2 = {(_Float16)z, (_Float16)z};
        #pragma unroll
        for (int half = 0; half < 2; ++half) {
            const int kt = g * 2 + half;
            #pragma unroll
            for (int i = 0; i < 4; ++i) {
                int off16 = i * 256 + tid;
                int row = off16 >> 3, sl = off16 & 7;
                const uint4* gsrc = xw + (size_t)(m0 + row) * KP + kt * 8 + sl;
                __builtin_amdgcn_global_load_lds(
                    (const __attribute__((address_space(1))) unsigned int*)gsrc,
                    (__attribute__((address_space(3))) unsigned int*)((char*)As + off16 * 16),
                    16, 0, 0);
            }
            uint4 qword = qp4[(size_t)(n0 + brow) * 128 + kt * 2 + bhalf];
            #pragma unroll
            for (int j = 0; j < 4; ++j) {
                unsigned int w = (j == 0) ? qword.x : (j == 1) ? qword.y : (j == 2) ? qword.z : qword.w;
                int sl = (bhalf * 4 + j) ^ (brow & 7);
                *(uint4*)((char*)Bs + brow * 128 + sl * 16) = dq8m(w, s2, z2);
            }
            __syncthreads();
            #pragma unroll
            for (int ks = 0; ks < 2; ++ks) {
                f16x8 a[4], b[4];
                #pragma unroll
                for (int m = 0; m < 4; ++m) {
                    int row = wm * 64 + m * 16 + l15;
                    int sl  = (ks * 4 + l4) ^ (row & 7);
                    a[m] = *(const f16x8*)((char*)As + row * 128 + sl * 16);
                }
                #pragma unroll
                for (int n = 0; n < 4; ++n) {
                    int row = wn * 64 + n * 16 + l15;
                    int sl  = (ks * 4 + l4) ^ (row & 7);
                    b[n] = *(const f16x8*)((char*)Bs + row * 128 + sl * 16);
                }
                #pragma unroll
                for (int m = 0; m < 4; ++m)
                    #pragma unroll
                    for (int n = 0; n < 4; ++n)
                        MFMA16(acc[m][n], a[m], b[n]);
            }
            __syncthreads();
        }
    }
    #pragma unroll
    for (int n = 0; n < 4; ++n) {
        int col = n0 + wn * 64 + n * 16 + l15;
        float bv = bias[col];
        #pragma unroll
        for (int m = 0; m < 4; ++m) {
            int rbase = m0 + wm * 64 + m * 16 + l4 * 4;
            #pragma unroll
            for (int j = 0; j < 4; ++j)
                out[(size_t)(rbase + j) * N_DIM + col] = acc[m][n][j] + bv;
        }
    }
}

extern "C" void kernel_launch(void* const* d_in, const int* in_sizes, int n_in,
                              void* d_out, int out_size, void* d_ws, size_t ws_size,
                              hipStream_t stream) {
    const float* x  = (const float*)d_in[0];
    const int*   qw = (const int*)d_in[1];
    const float* sc = (const float*)d_in[2];
    const float* zr = (const float*)d_in[3];
    const float* bi = (const float*)d_in[4];
    float* o = (float*)d_out;

    if (ws_size >= FULL_NEEDED) {
        uint4* wf = (uint4*)d_ws;
        uint4* xw = (uint4*)((char*)d_ws + XW2_OFFSET);
        prep<<<3072, 256, 0, stream>>>(qw, sc, zr, x, wf, xw);
        wq_gemm_8p1b<<<dim3(NWORK), dim3(512), 0, stream>>>(xw, wf, bi, o);
    } else {
        unsigned int* qp = (unsigned int*)d_ws;
        uint4* xw = (uint4*)((char*)d_ws + XW_OFFSET);
        pack_qw <<<2048, 256, 0, stream>>>(qw, qp);
        cvt_x_mid<<<2048, 256, 0, stream>>>(x, xw);
        dim3 grid(N_DIM / 128, M_DIM / 128);
        wq_gemm_packed<<<grid, dim3(256), 0, stream>>>((const uint4*)xw, (const uint4*)qp, sc, zr, bi, o);
    }
}

// Round 26
// 404.790 us; speedup vs baseline: 1.0768x; 1.0034x over previous
//
#include <hip/hip_runtime.h>
#include <stdint.h>

#define M_DIM 4096
#define K_DIM 4096
#define N_DIM 11008
#define KP    512              // 16B slots (8 fp16) per K row
#define NT    64               // K tiles of 64
#define NTILES 688             // 16 x 43 output tiles of 256x256
#define NWORK  512             // persistent blocks

// ---- FULL path ws layout: Wf fp16 [N][K] + xw fp16 [M][K] ----
#define XW2_OFFSET  92274688u
#define FULL_NEEDED (XW2_OFFSET + 33554432u)   // 125,829,120
// ---- MID path (round-4 proven) ws layout ----
#define XW_OFFSET  25165824u
#define WS_NEEDED  (XW_OFFSET + 33554432u)     // 58,720,256

typedef __attribute__((ext_vector_type(8))) _Float16 f16x8;
typedef __attribute__((ext_vector_type(2))) _Float16 f16x2;
typedef __attribute__((ext_vector_type(4))) float    f32x4;

#define MFMA16(d, va, vb) d = __builtin_amdgcn_mfma_f32_16x16x32_f16(va, vb, d, 0, 0, 0)

// ---------- fused pre-pass: dequant W -> wf slots; cvt x -> xw slots (both XOR-pre-swizzled) ----------
__global__ void prep(const int* __restrict__ qw, const float* __restrict__ sc,
                     const float* __restrict__ zr, const float* __restrict__ x,
                     uint4* __restrict__ wf, uint4* __restrict__ xw) {
    const int WUNITS = N_DIM * KP;
    const int TOT    = WUNITS + M_DIM * KP;
    int stride = gridDim.x * blockDim.x;
    for (int i = blockIdx.x * blockDim.x + threadIdx.x; i < TOT; i += stride) {
        if (i < WUNITS) {
            int n  = i >> 9;
            int sg = i & 511;
            const int* src = qw + (size_t)n * K_DIM + sg * 8;
            int4 a = *(const int4*)src;
            int4 b = *(const int4*)(src + 4);
            int g = sg >> 4;
            float s = sc[(size_t)g * N_DIM + n];
            float z = zr[(size_t)g * N_DIM + n];
            union { _Float16 h[8]; uint4 v; } pk;
            pk.h[0]=(_Float16)((float)a.x*s+z); pk.h[1]=(_Float16)((float)a.y*s+z);
            pk.h[2]=(_Float16)((float)a.z*s+z); pk.h[3]=(_Float16)((float)a.w*s+z);
            pk.h[4]=(_Float16)((float)b.x*s+z); pk.h[5]=(_Float16)((float)b.y*s+z);
            pk.h[6]=(_Float16)((float)b.z*s+z); pk.h[7]=(_Float16)((float)b.w*s+z);
            int dst = (sg & ~7) | ((sg & 7) ^ (n & 7));
            wf[((size_t)n << 9) + dst] = pk.v;
        } else {
            int j  = i - WUNITS;
            int m  = j >> 9;
            int sg = j & 511;
            const float* src = x + ((size_t)m << 12) + sg * 8;
            float4 f0 = *(const float4*)src;
            float4 f1 = *(const float4*)(src + 4);
            union { _Float16 h[8]; uint4 v; } pk;
            pk.h[0]=(_Float16)f0.x; pk.h[1]=(_Float16)f0.y;
            pk.h[2]=(_Float16)f0.z; pk.h[3]=(_Float16)f0.w;
            pk.h[4]=(_Float16)f1.x; pk.h[5]=(_Float16)f1.y;
            pk.h[6]=(_Float16)f1.z; pk.h[7]=(_Float16)f1.w;
            int dst = (sg & ~7) | ((sg & 7) ^ (m & 7));
            xw[((size_t)m << 9) + dst] = pk.v;
        }
    }
}

// ---------- FULL main GEMM: persistent, 256x256, 8 waves, 8-phase, ONE barrier/phase ----------
__global__ __launch_bounds__(512, 2) void wq_gemm_8p1b(
    const uint4* __restrict__ xw,    // fp16 [M][512] slots, pre-swizzled
    const uint4* __restrict__ wf,    // fp16 [N][512] slots, pre-swizzled
    const float* __restrict__ bias,
    float*       __restrict__ out)
{
    __shared__ __align__(16) uint4 Ls[2][2][2][1024];  // [buf][op][half][unit] 128KB

    const int tid  = threadIdx.x;
    const int lane = tid & 63;
    const int wid  = tid >> 6;          // 0..7
    const int wm   = wid >> 2;          // A half 0..1
    const int wn   = wid & 3;
    const int wbh  = wn >> 1;           // B half
    const int wbl  = wn & 1;            // 64-col slice within B half
    const int l15  = lane & 15;
    const int l4   = lane >> 4;

    for (int q = blockIdx.x; q < NTILES; q += NWORK) {
        // XCD-aware bijective swizzle on tile index
        int swz = (q & 7) * 86 + (q >> 3);
        const int m0 = (swz & 15) * 256;    // 16 m-blocks
        const int n0 = (swz >> 4) * 256;    // 43 n-blocks

        f32x4 acc[8][4] = {};

        auto stage = [&](int t, int buf, int op, int half) {
            const uint4* base = op ? (wf + (size_t)n0 * KP) : (xw + (size_t)m0 * KP);
            #pragma unroll
            for (int i = 0; i < 2; ++i) {
                int off = i * 512 + tid;            // 0..1023
                int row = off >> 3, sl = off & 7;
                const uint4* g = base + (size_t)(half * 128 + row) * KP + t * 8 + sl;
                __builtin_amdgcn_global_load_lds(
                    (const __attribute__((address_space(1))) unsigned int*)g,
                    (__attribute__((address_space(3))) unsigned int*)&Ls[buf][op][half][off],
                    16, 0, 0);
            }
        };

        f16x8 a[4][2], b[4][2];
        auto lda = [&](int buf, int mbase) {            // 8 ds_reads: a[0..3]
            const uint4* Ab = &Ls[buf][0][wm][0];
            #pragma unroll
            for (int mf = 0; mf < 4; ++mf) {
                int r = mbase + mf * 16 + l15;
                a[mf][0] = *(const f16x8*)(Ab + r * 8 + ((0 + l4) ^ (r & 7)));
                a[mf][1] = *(const f16x8*)(Ab + r * 8 + ((4 + l4) ^ (r & 7)));
            }
        };
        auto ldb = [&](int buf, int nf0) {              // 4 ds_reads: b[nf0..nf0+1]
            const uint4* Bb = &Ls[buf][1][wbh][0];
            #pragma unroll
            for (int nf = 0; nf < 2; ++nf) {
                int r = wbl * 64 + (nf0 + nf) * 16 + l15;
                b[nf0 + nf][0] = *(const f16x8*)(Bb + r * 8 + ((0 + l4) ^ (r & 7)));
                b[nf0 + nf][1] = *(const f16x8*)(Bb + r * 8 + ((4 + l4) ^ (r & 7)));
            }
        };

#define QUAD(MB, NB)                                                   \
        __builtin_amdgcn_s_setprio(1);                                 \
        _Pragma("unroll")                                              \
        for (int mf = 0; mf < 4; ++mf)                                 \
            _Pragma("unroll")                                          \
            for (int nf = 0; nf < 2; ++nf) {                           \
                MFMA16(acc[MB + mf][NB + nf], a[mf][0], b[NB + nf][0]);\
                MFMA16(acc[MB + mf][NB + nf], a[mf][1], b[NB + nf][1]);\
            }                                                          \
        __builtin_amdgcn_s_setprio(0);

#define BAR() __builtin_amdgcn_s_barrier()
#define VM4() asm volatile("s_waitcnt vmcnt(4)" ::: "memory")

        // ---- prologue: T0 (4 halves) + T1.B0,B1; drain T0 (keep T1.B flying) ----
        stage(0, 0, 0, 0); stage(0, 0, 0, 1); stage(0, 0, 1, 0); stage(0, 0, 1, 1);
        stage(1, 1, 1, 0); stage(1, 1, 1, 1);
        VM4();                                  // T0's 8 loads landed; T1.B's 4 in flight
        BAR();

        for (int it = 0; it < NT / 2; ++it) {
            const int T   = 2 * it;
            const int tp1 = T + 1;
            const int t2  = (T + 2 < NT) ? T + 2 : NT - 1;   // tail clamp: dead-region writes
            const int t3  = (T + 3 < NT) ? T + 3 : NT - 1;

            // One barrier per phase (end only): waves desync within the phase ->
            // LDS-read segment of late waves overlaps MFMA of early waves.
            // Race-audit: every stage target's last reader is >=1 collective
            // barrier earlier (A-stages: >=3; B-stages: 1). vmcnt publish = VM4+BAR.

            // p0: stage (T+1).A0; reads buf0 a(0-63)+b01; MFMA Q00
            stage(tp1, 1, 0, 0);
            lda(0, 0); ldb(0, 0);
            QUAD(0, 0); BAR();

            // p1: stage (T+1).A1; reads b23; MFMA Q02 (buf0.B dead after)
            stage(tp1, 1, 0, 1);
            ldb(0, 2);
            QUAD(0, 2); BAR();

            // p2: stage (T+2).B0 into buf0; reads a(64-127); MFMA Q42 (buf0.A dead after)
            stage(t2, 0, 1, 0);
            lda(0, 64);
            QUAD(4, 2); BAR();

            // p3: stage (T+2).B1; MFMA Q40; drain keeping 2 stages -> T+1 landed
            stage(t2, 0, 1, 1);
            QUAD(4, 0); VM4(); BAR();

            // p4: stage (T+2).A0; reads buf1 a(0-63)+b01; MFMA Q00
            stage(t2, 0, 0, 0);
            lda(1, 0); ldb(1, 0);
            QUAD(0, 0); BAR();

            // p5: stage (T+2).A1; reads b23; MFMA Q02
            stage(t2, 0, 0, 1);
            ldb(1, 2);
            QUAD(0, 2); BAR();

            // p6: stage (T+3).B0 into buf1; reads a(64-127); MFMA Q42
            stage(t3, 1, 1, 0);
            lda(1, 64);
            QUAD(4, 2); BAR();

            // p7: stage (T+3).B1; MFMA Q40; drain -> T+2 landed
            stage(t3, 1, 1, 1);
            QUAD(4, 0); VM4(); BAR();
        }

        asm volatile("s_waitcnt vmcnt(0)" ::: "memory");   // drain (0 outstanding at next prologue)

        // ---- epilogue ----
        #pragma unroll
        for (int nf = 0; nf < 4; ++nf) {
            int col = n0 + wbh * 128 + wbl * 64 + nf * 16 + l15;
            float bv = bias[col];
            #pragma unroll
            for (int mf = 0; mf < 8; ++mf) {
                int rbase = m0 + wm * 128 + mf * 16 + l4 * 4;
                #pragma unroll
                for (int j = 0; j < 4; ++j)
                    out[(size_t)(rbase + j) * N_DIM + col] = acc[mf][nf][j] + bv;
            }
        }
        BAR();   // all waves done with epilogue before next tile's staging overwrites LDS
#undef QUAD
#undef BAR
#undef VM4
    }
}

// ================= MID path (round-4 proven, 471 us) =================
__global__ void pack_qw(const int* __restrict__ qw, unsigned int* __restrict__ qp) {
    int stride = gridDim.x * blockDim.x;
    for (int i = blockIdx.x * blockDim.x + threadIdx.x; i < N_DIM * KP; i += stride) {
        const int* src = qw + (size_t)i * 8;
        int4 a = *(const int4*)src;
        int4 b = *(const int4*)(src + 4);
        unsigned int w = (unsigned)a.x | ((unsigned)a.z << 4) | ((unsigned)b.x << 8) | ((unsigned)b.z << 12)
                       | ((unsigned)a.y << 16) | ((unsigned)a.w << 20) | ((unsigned)b.y << 24) | ((unsigned)b.w << 28);
        qp[i] = w;
    }
}

__global__ void cvt_x_mid(const float* __restrict__ x, uint4* __restrict__ xw) {
    int stride = gridDim.x * blockDim.x;
    for (int i = blockIdx.x * blockDim.x + threadIdx.x; i < M_DIM * KP; i += stride) {
        int m  = i >> 9;
        int sg = i & 511;
        const float* src = x + ((size_t)m << 12) + sg * 8;
        float4 f0 = *(const float4*)src;
        float4 f1 = *(const float4*)(src + 4);
        union { _Float16 h[8]; uint4 v; } pk;
        pk.h[0]=(_Float16)f0.x; pk.h[1]=(_Float16)f0.y;
        pk.h[2]=(_Float16)f0.z; pk.h[3]=(_Float16)f0.w;
        pk.h[4]=(_Float16)f1.x; pk.h[5]=(_Float16)f1.y;
        pk.h[6]=(_Float16)f1.z; pk.h[7]=(_Float16)f1.w;
        int dst = (sg & ~7) | ((sg & 7) ^ (m & 7));
        xw[((size_t)m << 9) + dst] = pk.v;
    }
}

__device__ __forceinline__ uint4 dq8m(unsigned int w, f16x2 s2, f16x2 z2) {
    const f16x2 k1024 = {(_Float16)1024.0f, (_Float16)1024.0f};
    union { f16x2 h; unsigned int u; } p0, p1, p2, p3;
    p0.u = 0x64006400u | (w & 0x000F000Fu);
    p1.u = 0x64006400u | ((w >> 4)  & 0x000F000Fu);
    p2.u = 0x64006400u | ((w >> 8)  & 0x000F000Fu);
    p3.u = 0x64006400u | ((w >> 12) & 0x000F000Fu);
    union { f16x2 h2[4]; uint4 v; } r;
    r.h2[0] = (p0.h - k1024) * s2 + z2;
    r.h2[1] = (p1.h - k1024) * s2 + z2;
    r.h2[2] = (p2.h - k1024) * s2 + z2;
    r.h2[3] = (p3.h - k1024) * s2 + z2;
    return r.v;
}

__global__ __launch_bounds__(256, 3) void wq_gemm_packed(
    const uint4*  __restrict__ xw, const uint4* __restrict__ qp4,
    const float*  __restrict__ scales, const float* __restrict__ zeros,
    const float*  __restrict__ bias, float* __restrict__ out)
{
    __shared__ __align__(16) unsigned short As[128 * 64];
    __shared__ __align__(16) unsigned short Bs[128 * 64];
    const int tid = threadIdx.x, lane = tid & 63, wid = tid >> 6;
    const int wm = wid >> 1, wn = wid & 1, l15 = lane & 15, l4 = lane >> 4;
    const int m0 = blockIdx.y * 128, n0 = blockIdx.x * 128;
    const int brow = tid >> 1, bhalf = tid & 1;
    f32x4 acc[4][4] = {};
    for (int g = 0; g < 32; ++g) {
        float s = scales[(size_t)g * N_DIM + n0 + brow];
        float z = zeros [(size_t)g * N_DIM + n0 + brow];
        f16x2 s2 = {(_Float16)s, (_Float16)s};
        f16x2 z2 = {(_Float16)z, (_Float16)z};
        #pragma unroll
        for (int half = 0; half < 2; ++half) {
            const int kt = g * 2 + half;
            #pragma unroll
            for (int i = 0; i < 4; ++i) {
                int off16 = i * 256 + tid;
                int row = off16 >> 3, sl = off16 & 7;
                const uint4* gsrc = xw + (size_t)(m0 + row) * KP + kt * 8 + sl;
                __builtin_amdgcn_global_load_lds(
                    (const __attribute__((address_space(1))) unsigned int*)gsrc,
                    (__attribute__((address_space(3))) unsigned int*)((char*)As + off16 * 16),
                    16, 0, 0);
            }
            uint4 qword = qp4[(size_t)(n0 + brow) * 128 + kt * 2 + bhalf];
            #pragma unroll
            for (int j = 0; j < 4; ++j) {
                unsigned int w = (j == 0) ? qword.x : (j == 1) ? qword.y : (j == 2) ? qword.z : qword.w;
                int sl = (bhalf * 4 + j) ^ (brow & 7);
                *(uint4*)((char*)Bs + brow * 128 + sl * 16) = dq8m(w, s2, z2);
            }
            __syncthreads();
            #pragma unroll
            for (int ks = 0; ks < 2; ++ks) {
                f16x8 a[4], b[4];
                #pragma unroll
                for (int m = 0; m < 4; ++m) {
                    int row = wm * 64 + m * 16 + l15;
                    int sl  = (ks * 4 + l4) ^ (row & 7);
                    a[m] = *(const f16x8*)((char*)As + row * 128 + sl * 16);
                }
                #pragma unroll
                for (int n = 0; n < 4; ++n) {
                    int row = wn * 64 + n * 16 + l15;
                    int sl  = (ks * 4 + l4) ^ (row & 7);
                    b[n] = *(const f16x8*)((char*)Bs + row * 128 + sl * 16);
                }
                #pragma unroll
                for (int m = 0; m < 4; ++m)
                    #pragma unroll
                    for (int n = 0; n < 4; ++n)
                        MFMA16(acc[m][n], a[m], b[n]);
            }
            __syncthreads();
        }
    }
    #pragma unroll
    for (int n = 0; n < 4; ++n) {
        int col = n0 + wn * 64 + n * 16 + l15;
        float bv = bias[col];
        #pragma unroll
        for (int m = 0; m < 4; ++m) {
            int rbase = m0 + wm * 64 + m * 16 + l4 * 4;
            #pragma unroll
            for (int j = 0; j < 4; ++j)
                out[(size_t)(rbase + j) * N_DIM + col] = acc[m][n][j] + bv;
        }
    }
}

extern "C" void kernel_launch(void* const* d_in, const int* in_sizes, int n_in,
                              void* d_out, int out_size, void* d_ws, size_t ws_size,
                              hipStream_t stream) {
    const float* x  = (const float*)d_in[0];
    const int*   qw = (const int*)d_in[1];
    const float* sc = (const float*)d_in[2];
    const float* zr = (const float*)d_in[3];
    const float* bi = (const float*)d_in[4];
    float* o = (float*)d_out;

    if (ws_size >= FULL_NEEDED) {
        uint4* wf = (uint4*)d_ws;
        uint4* xw = (uint4*)((char*)d_ws + XW2_OFFSET);
        prep<<<3072, 256, 0, stream>>>(qw, sc, zr, x, wf, xw);
        wq_gemm_8p1b<<<dim3(NWORK), dim3(512), 0, stream>>>(xw, wf, bi, o);
    } else {
        unsigned int* qp = (unsigned int*)d_ws;
        uint4* xw = (uint4*)((char*)d_ws + XW_OFFSET);
        pack_qw <<<2048, 256, 0, stream>>>(qw, qp);
        cvt_x_mid<<<2048, 256, 0, stream>>>(x, xw);
        dim3 grid(N_DIM / 128, M_DIM / 128);
        wq_gemm_packed<<<grid, dim3(256), 0, stream>>>((const uint4*)xw, (const uint4*)qp, sc, zr, bi, o);
    }
}